// Round 9
// baseline (107.839 us; speedup 1.0000x reference)
//
#include <hip/hip_runtime.h>

#define HW    3136   // 56*56
#define HW4   784    // float4 per (b,c) row = 12*64 + 16
#define C     512
#define B     32
#define ROWS  (B * C)   // 16384

typedef float floatx4 __attribute__((ext_vector_type(4)));

// Pass 1: one wave per (b,c) row. 12 unrolled dwordx4 loads + 16-lane tail,
// butterfly reduce. (Unchanged from round 8.)
__global__ __launch_bounds__(256) void se_mean_kernel(const float* __restrict__ x,
                                                      float* __restrict__ y) {
    const int wave = threadIdx.x >> 6;
    const int lane = threadIdx.x & 63;
    const int row  = blockIdx.x * 4 + wave;   // [0, 16384)
    const floatx4* xr = reinterpret_cast<const floatx4*>(x) + (size_t)row * HW4;

    float s = 0.f;
    #pragma unroll
    for (int k = 0; k < 12; ++k) {            // 12*64 = 768 float4, uniform
        floatx4 v = xr[lane + 64 * k];
        s += (v.x + v.y) + (v.z + v.w);
    }
    if (lane < 16) {                          // float4 768..783
        floatx4 v = xr[768 + lane];
        s += (v.x + v.y) + (v.z + v.w);
    }
    #pragma unroll
    for (int off = 32; off; off >>= 1) s += __shfl_down(s, off, 64);
    if (lane == 0) y[row] = s * (1.0f / HW);
}

// Pass 2: identical to round 8 EXCEPT stores are PLAIN (not nt).
// Single-variable A/B: does the nt policy cap write BW (Model A), or is the
// scale pass fabric-limited regardless (Model B), or does write-allocate
// evict x and kill the L3 re-read (Model C)?
__global__ __launch_bounds__(256) void se_scale_kernel(const float* __restrict__ x,
                                                       const float* __restrict__ y,
                                                       const float* __restrict__ W,
                                                       const float* __restrict__ bias,
                                                       float* __restrict__ out) {
    const int row0 = (gridDim.x - 1 - blockIdx.x) * 8;  // reverse order
    const int b    = row0 >> 9;
    const int m    = (row0 & (C - 1)) >> 6;
    const int wave = threadIdx.x >> 6;
    const int lane = threadIdx.x & 63;

    // gate: 512-length dot, 8 FMA per lane, butterfly so every lane has it
    const float* yb = y + b * C;
    const float* wm = W + m * C;
    float s = 0.f;
    #pragma unroll
    for (int i = 0; i < 8; ++i) s = fmaf(yb[lane + 64 * i], wm[lane + 64 * i], s);
    #pragma unroll
    for (int off = 32; off; off >>= 1) s += __shfl_xor(s, off, 64);
    s += bias[m];
    s = fmaxf(s, 0.f);                          // relu
    const float g = 1.0f / (1.0f + expf(-s));   // sigmoid

    // scale 2 rows per wave, unrolled 12 + tail, PLAIN stores
    #pragma unroll
    for (int r = 0; r < 2; ++r) {
        const int row = row0 + wave * 2 + r;
        const floatx4* xr  = reinterpret_cast<const floatx4*>(x) + (size_t)row * HW4;
        floatx4*      orow = reinterpret_cast<floatx4*>(out)     + (size_t)row * HW4;
        #pragma unroll
        for (int k = 0; k < 12; ++k) {
            floatx4 v = xr[lane + 64 * k];
            v *= g;
            orow[lane + 64 * k] = v;
        }
        if (lane < 16) {
            floatx4 v = xr[768 + lane];
            v *= g;
            orow[768 + lane] = v;
        }
    }
}

extern "C" void kernel_launch(void* const* d_in, const int* in_sizes, int n_in,
                              void* d_out, int out_size, void* d_ws, size_t ws_size,
                              hipStream_t stream) {
    const float* x    = (const float*)d_in[0];  // (32,512,56,56)
    const float* W    = (const float*)d_in[1];  // (8,512)
    const float* bias = (const float*)d_in[2];  // (8,)
    float* out = (float*)d_out;

    float* y = (float*)d_ws;                    // 16384 floats = 64 KB

    se_mean_kernel <<<ROWS / 4, 256, 0, stream>>>(x, y);
    se_scale_kernel<<<ROWS / 8, 256, 0, stream>>>(x, y, W, bias, out);
}